// Round 11
// baseline (818.472 us; speedup 1.0000x reference)
//
#include <hip/hip_runtime.h>
#include <hip/hip_cooperative_groups.h>

namespace cg = cooperative_groups;

#define H 128
#define NSRC 3
#define MSTRIDE 132   // padded f16 row stride: 264 B -> conflict-free vs 32 banks

typedef _Float16 f16;
typedef _Float16 f16x2 __attribute__((ext_vector_type(2)));
typedef _Float16 f16x4 __attribute__((ext_vector_type(4)));
typedef _Float16 f16x8 __attribute__((ext_vector_type(8)));
typedef float f32x4 __attribute__((ext_vector_type(4)));

#define PREP_BLOCKS 1024
#define PREP_THREADS 256

// ---------------------------------------------------------------------------
// ONE cooperative prep kernel:
//  phase0: zero cnt, zero AGG, W fp32->f16 transposed+pre-swizzled, NF->f16
//  phase1: histogram of receivers
//  phase2: grid-level exclusive scan -> rowptr/cursor (two-level)
//  phase3: scatter -> perm/ssend/srecv (counting sort by receiver)
// ---------------------------------------------------------------------------
__global__ __launch_bounds__(PREP_THREADS)
void prep_kernel(const float* __restrict__ W, f16* __restrict__ wbuf,
                 const float* __restrict__ nf, f16* __restrict__ nfh, int nf4,
                 const int* __restrict__ senders, const int* __restrict__ receivers,
                 int n_edges, int* __restrict__ cnt, int* __restrict__ rowptr,
                 int* __restrict__ cursor, int* __restrict__ perm,
                 int* __restrict__ ssend, int* __restrict__ srecv,
                 int* __restrict__ partials, int n_nodes,
                 float4* __restrict__ AGG4, int nagg4) {
    cg::grid_group grid = cg::this_grid();
    const int gid = blockIdx.x * blockDim.x + threadIdx.x;
    const int np = gridDim.x * blockDim.x;

    // ---- phase 0 ----
    for (int i = gid; i < n_nodes; i += np) cnt[i] = 0;
    for (int i = gid; i < NSRC * H * H; i += np) {
        int src = i >> 14;
        int k = (i >> 7) & 127;
        int c = i & 127;
        float v = W[((size_t)src * H + k) * H + c];
        unsigned off = ((unsigned)(c * 256 + k * 2)) ^ ((unsigned)((c & 7) << 4));
        wbuf[(size_t)src * (H * H) + (off >> 1)] = (f16)v;
    }
    for (int j = gid; j < nf4; j += np) {
        float4 v = ((const float4*)nf)[j];
        f16x4 h;
        h[0] = (f16)v.x; h[1] = (f16)v.y; h[2] = (f16)v.z; h[3] = (f16)v.w;
        ((f16x4*)nfh)[j] = h;
    }
    for (int j = gid; j < nagg4; j += np)
        AGG4[j] = make_float4(0.f, 0.f, 0.f, 0.f);
    grid.sync();

    // ---- phase 1: histogram ----
    for (int e = gid; e < n_edges; e += np)
        atomicAdd(&cnt[receivers[e]], 1);
    grid.sync();

    // ---- phase 2a: per-block chunk scan (wave 0 of each block) ----
    __shared__ int sl[64];
    const int chunk = (n_nodes + gridDim.x - 1) / gridDim.x;  // <= 64 required
    const int cbeg = blockIdx.x * chunk;
    const int nloc = min(chunk, n_nodes - cbeg);
    if (threadIdx.x < 64) {
        const int lane = threadIdx.x;
        int v = (lane < nloc) ? cnt[cbeg + lane] : 0;
#pragma unroll
        for (int d = 1; d < 64; d <<= 1) {
            int u = __shfl_up(v, d);
            if (lane >= d) v += u;
        }
        sl[lane] = v;  // inclusive scan of this block's chunk
        if (lane == 63) partials[blockIdx.x] = v;  // block total
    }
    grid.sync();

    // ---- phase 2b: block 0 scans partials -> exclusive prefixes ----
    if (blockIdx.x == 0) {
        const int t = threadIdx.x;
        const int t4 = t * 4;
        int p0 = partials[t4], p1 = partials[t4 + 1],
            p2 = partials[t4 + 2], p3 = partials[t4 + 3];
        int s = p0 + p1 + p2 + p3;
        int v = s;
        const int lane = t & 63, w = t >> 6;
#pragma unroll
        for (int d = 1; d < 64; d <<= 1) {
            int u = __shfl_up(v, d);
            if (lane >= d) v += u;
        }
        __shared__ int wtot[4];
        if (lane == 63) wtot[w] = v;
        __syncthreads();
        int wbase = 0;
        for (int i = 0; i < w; ++i) wbase += wtot[i];
        int excl = wbase + v - s;
        partials[t4] = excl;
        partials[t4 + 1] = excl + p0;
        partials[t4 + 2] = excl + p0 + p1;
        partials[t4 + 3] = excl + p0 + p1 + p2;
        if (t == 255) partials[PREP_BLOCKS] = excl + s;  // grand total
    }
    grid.sync();

    // ---- phase 2c: write rowptr/cursor ----
    if (threadIdx.x < 64) {
        const int lane = threadIdx.x;
        const int base = partials[blockIdx.x];
        if (lane < nloc) {
            int excl = sl[lane] - cnt[cbeg + lane];
            rowptr[cbeg + lane] = base + excl;
            cursor[cbeg + lane] = base + excl;
        }
        if (blockIdx.x == 0 && lane == 0)
            rowptr[n_nodes] = partials[PREP_BLOCKS];
    }
    grid.sync();

    // ---- phase 3: scatter ----
    for (int e = gid; e < n_edges; e += np) {
        int r = receivers[e];
        int pos = atomicAdd(&cursor[r], 1);
        perm[pos] = e;
        ssend[pos] = senders[e];
        srecv[pos] = r;
    }
}

// ---------------------------------------------------------------------------
// FUSED full-K message kernel over sorted edges, SOFTWARE-PIPELINED.
// Per 64-edge tile: stage A (3 sources, f16, XOR-swizzled LDS), MFMA K=384
// (W in registers), MSG transpose via padded LDS, segmented reduce with one
// atomicAdd pair per lane per receiver segment. EF + sender + RECEIVER rows
// and indices for tile t+1 prefetched into registers during tile t compute.
// ---------------------------------------------------------------------------
__global__ __launch_bounds__(256, 2)
void fused_msg_kernel(const f16* __restrict__ nfh, const float* __restrict__ ef,
                      const int* __restrict__ perm, const int* __restrict__ ssend,
                      const int* __restrict__ srecv, const f16* __restrict__ wbuf,
                      const float* __restrict__ b, float* __restrict__ AGG,
                      int n_edges) {
    __shared__ __align__(16) f16 Alds[NSRC * 64 * H];  // 48 KB
    __shared__ __align__(16) f16 MSG[64 * MSTRIDE];    // 16.5 KB
    __shared__ int SR[64];

    const int t = threadIdx.x;
    const int lane = t & 63;
    const int wid = t >> 6;     // 0..3
    const int l15 = lane & 15;
    const int lg = lane >> 4;
    const int c2 = lane * 2;

    // ---- W fragments in registers: [src][cf][ks], this wave's 32 cols ----
    f16x8 breg[NSRC][2][4];
#pragma unroll
    for (int src = 0; src < NSRC; ++src)
#pragma unroll
        for (int cf = 0; cf < 2; ++cf)
#pragma unroll
            for (int ks = 0; ks < 4; ++ks) {
                const int c = wid * 32 + cf * 16 + l15;
                const int k = ks * 32 + lg * 8;
                unsigned off = ((unsigned)(c * 256 + k * 2)) ^ ((unsigned)((c & 7) << 4));
                breg[src][cf][ks] =
                    *(const f16x8*)((const char*)wbuf + (size_t)src * 32768 + off);
            }

    const float2 bias2 = *(const float2*)&b[c2];
    const int srow = t >> 2;   // staging row 0..63
    const int sq = t & 3;      // staging k-quarter
    const int ntiles = (n_edges + 63) >> 6;
    const int stride = gridDim.x;

    // ---- pipeline registers (all static names) ----
    int cr = 0;                                 // current receiver (for SR)
    int ns = 0, nr = 0, npx = 0;                // indices, next tile
    int4 s0, s1, s2, s3;                        // sender row quarter (64 B f16)
    int4 r0, r1, r2, r3;                        // receiver row quarter (64 B f16)
    float4 e0, e1, e2, e3, e4, e5, e6, e7;      // EF row quarter (128 B fp32)

    int tile = blockIdx.x;
    if (tile < ntiles) {
        const int e = min(tile * 64 + srow, n_edges - 1);
        int cs = ssend[e]; cr = srecv[e]; int cp = perm[e];
        const int4* ps = (const int4*)(nfh + (size_t)cs * H + sq * 32);
        s0 = ps[0]; s1 = ps[1]; s2 = ps[2]; s3 = ps[3];
        const int4* pr = (const int4*)(nfh + (size_t)cr * H + sq * 32);
        r0 = pr[0]; r1 = pr[1]; r2 = pr[2]; r3 = pr[3];
        const float4* pe = (const float4*)(ef + (size_t)cp * H + sq * 32);
        e0 = pe[0]; e1 = pe[1]; e2 = pe[2]; e3 = pe[3];
        e4 = pe[4]; e5 = pe[5]; e6 = pe[6]; e7 = pe[7];
    }
    if (tile + stride < ntiles) {
        const int e = min((tile + stride) * 64 + srow, n_edges - 1);
        ns = ssend[e]; nr = srecv[e]; npx = perm[e];
    }

    for (; tile < ntiles; tile += stride) {
        const int e0base = tile * 64;
        __syncthreads();  // Alds free (prev MFMA done), MSG free (prev reduce done)

        // ---- stage: write prefetched sender + receiver + EF data ----
        {
            unsigned off0 = ((unsigned)(srow * 256 + (sq * 32 + 0) * 2)) ^ ((unsigned)((srow & 7) << 4));
            unsigned off1 = ((unsigned)(srow * 256 + (sq * 32 + 8) * 2)) ^ ((unsigned)((srow & 7) << 4));
            unsigned off2 = ((unsigned)(srow * 256 + (sq * 32 + 16) * 2)) ^ ((unsigned)((srow & 7) << 4));
            unsigned off3 = ((unsigned)(srow * 256 + (sq * 32 + 24) * 2)) ^ ((unsigned)((srow & 7) << 4));
            *(int4*)((char*)Alds + off0) = s0;
            *(int4*)((char*)Alds + off1) = s1;
            *(int4*)((char*)Alds + off2) = s2;
            *(int4*)((char*)Alds + off3) = s3;
            *(int4*)((char*)Alds + 16384 + off0) = r0;
            *(int4*)((char*)Alds + 16384 + off1) = r1;
            *(int4*)((char*)Alds + 16384 + off2) = r2;
            *(int4*)((char*)Alds + 16384 + off3) = r3;
            f16x8 h0, h1, h2, h3;
#pragma unroll
            for (int j = 0; j < 4; ++j) { h0[j] = (f16)(&e0.x)[j]; h0[j + 4] = (f16)(&e1.x)[j]; }
#pragma unroll
            for (int j = 0; j < 4; ++j) { h1[j] = (f16)(&e2.x)[j]; h1[j + 4] = (f16)(&e3.x)[j]; }
#pragma unroll
            for (int j = 0; j < 4; ++j) { h2[j] = (f16)(&e4.x)[j]; h2[j + 4] = (f16)(&e5.x)[j]; }
#pragma unroll
            for (int j = 0; j < 4; ++j) { h3[j] = (f16)(&e6.x)[j]; h3[j + 4] = (f16)(&e7.x)[j]; }
            *(f16x8*)((char*)Alds + 32768 + off0) = h0;
            *(f16x8*)((char*)Alds + 32768 + off1) = h1;
            *(f16x8*)((char*)Alds + 32768 + off2) = h2;
            *(f16x8*)((char*)Alds + 32768 + off3) = h3;
            if (sq == 0) SR[srow] = cr;
        }

        // ---- issue prefetches for next tiles (fly under MFMA + reduce) ----
        int t2s = 0, t2r = 0, t2p = 0;
        if (tile + 2 * stride < ntiles) {
            const int e = min((tile + 2 * stride) * 64 + srow, n_edges - 1);
            t2s = ssend[e]; t2r = srecv[e]; t2p = perm[e];
        }
        if (tile + stride < ntiles) {
            const int4* ps = (const int4*)(nfh + (size_t)ns * H + sq * 32);
            s0 = ps[0]; s1 = ps[1]; s2 = ps[2]; s3 = ps[3];
            const int4* pr = (const int4*)(nfh + (size_t)nr * H + sq * 32);
            r0 = pr[0]; r1 = pr[1]; r2 = pr[2]; r3 = pr[3];
            const float4* pe = (const float4*)(ef + (size_t)npx * H + sq * 32);
            e0 = pe[0]; e1 = pe[1]; e2 = pe[2]; e3 = pe[3];
            e4 = pe[4]; e5 = pe[5]; e6 = pe[6]; e7 = pe[7];
        }
        __syncthreads();  // Alds ready

        // ---- MFMA: 64 rows x this wave's 32 cols, K=384 ----
        f32x4 acc[4][2];
#pragma unroll
        for (int rf = 0; rf < 4; ++rf) {
            acc[rf][0] = (f32x4){0.f, 0.f, 0.f, 0.f};
            acc[rf][1] = (f32x4){0.f, 0.f, 0.f, 0.f};
        }
#pragma unroll
        for (int src = 0; src < NSRC; ++src)
#pragma unroll
            for (int ks = 0; ks < 4; ++ks) {
                f16x8 af[4];
#pragma unroll
                for (int rf = 0; rf < 4; ++rf) {
                    const int row = rf * 16 + l15;
                    const int k = ks * 32 + lg * 8;
                    unsigned off = ((unsigned)(row * 256 + k * 2))
                                   ^ ((unsigned)((row & 7) << 4));
                    af[rf] = *(const f16x8*)((const char*)Alds + (size_t)src * 16384 + off);
                }
#pragma unroll
                for (int rf = 0; rf < 4; ++rf) {
                    acc[rf][0] = __builtin_amdgcn_mfma_f32_16x16x32_f16(
                        af[rf], breg[src][0][ks], acc[rf][0], 0, 0, 0);
                    acc[rf][1] = __builtin_amdgcn_mfma_f32_16x16x32_f16(
                        af[rf], breg[src][1][ks], acc[rf][1], 0, 0, 0);
                }
            }

        // ---- MSG transpose (C/D: col=l15, row=lg*4+q) ----
#pragma unroll
        for (int rf = 0; rf < 4; ++rf)
#pragma unroll
            for (int cf = 0; cf < 2; ++cf)
#pragma unroll
                for (int q = 0; q < 4; ++q)
                    MSG[(rf * 16 + lg * 4 + q) * MSTRIDE + wid * 32 + cf * 16 + l15] =
                        (f16)acc[rf][cf][q];
        __syncthreads();

        // ---- segmented reduce: wave wid owns rows wid*16..+16 ----
        int rarr[16];
#pragma unroll
        for (int j = 0; j < 16; ++j) rarr[j] = SR[wid * 16 + j];
        float ax = 0.f, ay = 0.f;
#pragma unroll
        for (int j = 0; j < 16; ++j) {
            const int e = e0base + wid * 16 + j;
            if (e < n_edges) {
                f16x2 m = *(const f16x2*)&MSG[(wid * 16 + j) * MSTRIDE + c2];
                ax += fmaxf((float)m[0] + bias2.x, 0.f);
                ay += fmaxf((float)m[1] + bias2.y, 0.f);
                bool flush = (j == 15) || (e + 1 >= n_edges) || (rarr[j + 1] != rarr[j]);
                if (flush) {
                    atomicAdd(&AGG[(size_t)rarr[j] * H + c2], ax);
                    atomicAdd(&AGG[(size_t)rarr[j] * H + c2 + 1], ay);
                    ax = 0.f;
                    ay = 0.f;
                }
            }
        }

        // ---- rotate pipeline registers ----
        cr = nr;
        ns = t2s; nr = t2r; npx = t2p;
    }
}

// ---------------------------------------------------------------------------
// LayerNorm(nf + AGG) -> out
// ---------------------------------------------------------------------------
__global__ __launch_bounds__(256, 4)
void ln_agg_kernel(const float* __restrict__ nf, const float* __restrict__ AGG,
                   const float* __restrict__ lnw, const float* __restrict__ lnb,
                   float* __restrict__ out, int n_nodes) {
    const int wv = threadIdx.x >> 6;
    const int lane = threadIdx.x & 63;
    const int row = blockIdx.x * (blockDim.x >> 6) + wv;
    if (row >= n_nodes) return;
    float2 a = ((const float2*)(nf + (size_t)row * H))[lane];
    float2 g = ((const float2*)(AGG + (size_t)row * H))[lane];
    float vx = a.x + g.x, vy = a.y + g.y;

    float s = vx + vy;
#pragma unroll
    for (int m = 32; m; m >>= 1) s += __shfl_xor(s, m, 64);
    float mu = s * (1.f / H);
    float dx = vx - mu, dy = vy - mu;
    float q = dx * dx + dy * dy;
#pragma unroll
    for (int m = 32; m; m >>= 1) q += __shfl_xor(q, m, 64);
    float rs = rsqrtf(q * (1.f / H) + 1e-5f);

    float2 w2 = ((const float2*)lnw)[lane];
    float2 b2 = ((const float2*)lnb)[lane];
    float2 o;
    o.x = dx * rs * w2.x + b2.x;
    o.y = dy * rs * w2.y + b2.y;
    ((float2*)(out + (size_t)row * H))[lane] = o;
}

// ---------------------------------------------------------------------------
// Fallback (small ws): naive edge pass + LN
// ---------------------------------------------------------------------------
__global__ void naive_edge_kernel(const float* __restrict__ nf, const int* __restrict__ s,
                                  const int* __restrict__ r, const float* __restrict__ ef,
                                  const float* __restrict__ W, const float* __restrict__ b,
                                  float* __restrict__ out, int n_edges) {
    int e = blockIdx.x * 2 + (threadIdx.x >> 7);
    int c = threadIdx.x & 127;
    if (e >= n_edges) return;
    int se = s[e], re = r[e];
    float acc = b[c];
    for (int k = 0; k < H; ++k) {
        acc += nf[(size_t)se * H + k] * W[(size_t)k * H + c];
        acc += nf[(size_t)re * H + k] * W[(size_t)(H + k) * H + c];
        acc += ef[(size_t)e * H + k] * W[(size_t)(2 * H + k) * H + c];
    }
    atomicAdd(&out[(size_t)re * H + c], fmaxf(acc, 0.f));
}

__global__ __launch_bounds__(256, 4)
void ln_kernel(const float* __restrict__ nf, const float* __restrict__ lnw,
               const float* __restrict__ lnb, float* __restrict__ out, int n_nodes) {
    const int wv = threadIdx.x >> 6;
    const int lane = threadIdx.x & 63;
    const int row = blockIdx.x * (blockDim.x >> 6) + wv;
    if (row >= n_nodes) return;
    float2 a = ((const float2*)(nf + (size_t)row * H))[lane];
    float2 g = ((float2*)(out + (size_t)row * H))[lane];
    float vx = a.x + g.x, vy = a.y + g.y;
    float s = vx + vy;
#pragma unroll
    for (int m = 32; m; m >>= 1) s += __shfl_xor(s, m, 64);
    float mu = s * (1.f / H);
    float dx = vx - mu, dy = vy - mu;
    float q = dx * dx + dy * dy;
#pragma unroll
    for (int m = 32; m; m >>= 1) q += __shfl_xor(q, m, 64);
    float rs = rsqrtf(q * (1.f / H) + 1e-5f);
    float2 w2 = ((const float2*)lnw)[lane];
    float2 b2 = ((const float2*)lnb)[lane];
    float2 o;
    o.x = dx * rs * w2.x + b2.x;
    o.y = dy * rs * w2.y + b2.y;
    ((float2*)(out + (size_t)row * H))[lane] = o;
}

// ---------------------------------------------------------------------------
extern "C" void kernel_launch(void* const* d_in, const int* in_sizes, int n_in,
                              void* d_out, int out_size, void* d_ws, size_t ws_size,
                              hipStream_t stream) {
    const float* nf        = (const float*)d_in[0];
    const int*   senders   = (const int*)d_in[1];
    const int*   receivers = (const int*)d_in[2];
    const float* ef        = (const float*)d_in[3];
    const float* W         = (const float*)d_in[4];
    const float* b         = (const float*)d_in[5];
    const float* lnw       = (const float*)d_in[6];
    const float* lnb       = (const float*)d_in[7];
    float* out = (float*)d_out;

    const int n_nodes = in_sizes[0] / H;  // 50000
    const int n_edges = in_sizes[1];      // 800000
    const int nfelem = n_nodes * H;

    // ws carve-out (256B aligned)
    size_t o = 0;
    auto carve = [&](size_t bytes) { size_t r = o; o += (bytes + 255) & ~(size_t)255; return r; };
    const size_t o_wbuf   = carve((size_t)NSRC * H * H * sizeof(f16));   // 96 KB
    const size_t o_nfh    = carve((size_t)nfelem * sizeof(f16));         // 12.8 MB
    const size_t o_cnt    = carve((size_t)n_nodes * 4);
    const size_t o_rowptr = carve((size_t)(n_nodes + 1) * 4);
    const size_t o_cursor = carve((size_t)n_nodes * 4);
    const size_t o_part   = carve((size_t)(PREP_BLOCKS + 1) * 4);
    const size_t o_perm   = carve((size_t)n_edges * 4);
    const size_t o_ssend  = carve((size_t)n_edges * 4);
    const size_t o_srecv  = carve((size_t)n_edges * 4);
    const size_t o_agg    = carve((size_t)nfelem * sizeof(float));       // 25.6 MB
    const size_t need_full = o;

    char* ws = (char*)d_ws;

    if (ws_size >= need_full) {
        f16* wbuf   = (f16*)(ws + o_wbuf);
        f16* nfh    = (f16*)(ws + o_nfh);
        int* cnt    = (int*)(ws + o_cnt);
        int* rowptr = (int*)(ws + o_rowptr);
        int* cursor = (int*)(ws + o_cursor);
        int* part   = (int*)(ws + o_part);
        int* perm   = (int*)(ws + o_perm);
        int* ssendb = (int*)(ws + o_ssend);
        int* srecvb = (int*)(ws + o_srecv);
        float* AGG  = (float*)(ws + o_agg);

        int nf4 = nfelem / 4;
        int nagg4 = nfelem / 4;
        float4* AGG4 = (float4*)AGG;
        void* args[] = {
            (void*)&W, (void*)&wbuf, (void*)&nf, (void*)&nfh, (void*)&nf4,
            (void*)&senders, (void*)&receivers, (void*)&n_edges,
            (void*)&cnt, (void*)&rowptr, (void*)&cursor, (void*)&perm,
            (void*)&ssendb, (void*)&srecvb, (void*)&part, (void*)&n_nodes,
            (void*)&AGG4, (void*)&nagg4
        };
        hipLaunchCooperativeKernel((void*)prep_kernel, dim3(PREP_BLOCKS),
                                   dim3(PREP_THREADS), args, 0, stream);

        fused_msg_kernel<<<1024, 256, 0, stream>>>(nfh, ef, perm, ssendb, srecvb,
                                                   wbuf, b, AGG, n_edges);
        ln_agg_kernel<<<(n_nodes + 3) / 4, 256, 0, stream>>>(nf, AGG, lnw, lnb, out, n_nodes);
    } else {
        hipMemsetAsync(d_out, 0, (size_t)nfelem * sizeof(float), stream);
        naive_edge_kernel<<<(n_edges + 1) / 2, 256, 0, stream>>>(
            nf, senders, receivers, ef, W, b, out, n_edges);
        ln_kernel<<<(n_nodes + 3) / 4, 256, 0, stream>>>(nf, lnw, lnb, out, n_nodes);
    }
}

// Round 12
// 383.458 us; speedup vs baseline: 2.1345x; 2.1345x over previous
//
#include <hip/hip_runtime.h>

#define H 128
#define NSRC 3
#define MSTRIDE 132   // padded f16 row stride: 264 B -> conflict-free vs 32 banks

typedef _Float16 f16;
typedef _Float16 f16x2 __attribute__((ext_vector_type(2)));
typedef _Float16 f16x4 __attribute__((ext_vector_type(4)));
typedef _Float16 f16x8 __attribute__((ext_vector_type(8)));
typedef float f32x4 __attribute__((ext_vector_type(4)));

// ---------------------------------------------------------------------------
// setup: prep W (fp32 [384][128] -> f16 [c][k] transposed, PRE-SWIZZLED:
// byte off within src = (c*256 + k*2) ^ ((c&7)<<4)), zero cnt, zero AGG,
// convert NF fp32 -> f16 (nfh).
// ---------------------------------------------------------------------------
__global__ void setup_kernel(const float* __restrict__ W, f16* __restrict__ wbuf,
                             int* __restrict__ cnt, float4* __restrict__ AGG4,
                             int n_nodes, int nagg4,
                             const float* __restrict__ nf, f16* __restrict__ nfh,
                             int nf4) {
    const int i = blockIdx.x * blockDim.x + threadIdx.x;
    const int np = gridDim.x * blockDim.x;
    if (i < NSRC * H * H) {
        int src = i >> 14;
        int k = (i >> 7) & 127;
        int c = i & 127;
        float v = W[((size_t)src * H + k) * H + c];
        unsigned off = ((unsigned)(c * 256 + k * 2)) ^ ((unsigned)((c & 7) << 4));
        wbuf[(size_t)src * (H * H) + (off >> 1)] = (f16)v;
    }
    if (i < n_nodes) cnt[i] = 0;
    for (int j = i; j < nagg4; j += np) AGG4[j] = make_float4(0.f, 0.f, 0.f, 0.f);
    for (int j = i; j < nf4; j += np) {
        float4 v = ((const float4*)nf)[j];
        f16x4 h;
        h[0] = (f16)v.x; h[1] = (f16)v.y; h[2] = (f16)v.z; h[3] = (f16)v.w;
        ((f16x4*)nfh)[j] = h;
    }
}

// ---------------------------------------------------------------------------
// Counting sort by receiver: hist -> scan -> scatter (ssr = packed {send,recv})
// ---------------------------------------------------------------------------
__global__ void hist_kernel(const int* __restrict__ recv, int* __restrict__ cnt, int n_edges) {
    int e = (blockIdx.x * blockDim.x + threadIdx.x) * 4;
    if (e + 3 < n_edges) {
        int4 r = *(const int4*)&recv[e];
        atomicAdd(&cnt[r.x], 1);
        atomicAdd(&cnt[r.y], 1);
        atomicAdd(&cnt[r.z], 1);
        atomicAdd(&cnt[r.w], 1);
    } else {
        for (int j = e; j < n_edges; ++j) atomicAdd(&cnt[recv[j]], 1);
    }
}

__global__ void scan_kernel(const int* __restrict__ cnt, int* __restrict__ row_ptr,
                            int* __restrict__ cursor, int n) {
    __shared__ int sd[1024];
    const int t = threadIdx.x;
    const int per = (n + 1023) >> 10;
    const int st = t * per;
    const int en = min(st + per, n);
    int s = 0;
    for (int i = st; i < en; ++i) s += cnt[i];
    sd[t] = s;
    __syncthreads();
    for (int off = 1; off < 1024; off <<= 1) {
        int v = 0;
        if (t >= off) v = sd[t - off];
        __syncthreads();
        sd[t] += v;
        __syncthreads();
    }
    int run = sd[t] - s;
    for (int i = st; i < en; ++i) {
        row_ptr[i] = run;
        cursor[i] = run;
        run += cnt[i];
    }
    if (t == 1023) row_ptr[n] = sd[1023];
}

__global__ void scatter_kernel(const int* __restrict__ send, const int* __restrict__ recv,
                               int* __restrict__ cursor, int* __restrict__ perm,
                               int2* __restrict__ ssr, int n_edges) {
    int e = blockIdx.x * blockDim.x + threadIdx.x;
    if (e < n_edges) {
        int r = recv[e];
        int pos = atomicAdd(&cursor[r], 1);
        perm[pos] = e;
        ssr[pos] = make_int2(send[e], r);
    }
}

// ---------------------------------------------------------------------------
// FUSED full-K message kernel over sorted edges, SOFTWARE-PIPELINED (3 deep).
// Per 64-edge tile: stage A (3 sources, f16, XOR-swizzled LDS), MFMA K=384
// (W in registers), MSG transpose via padded LDS, segmented reduce with one
// atomicAdd pair per lane per receiver segment. EF + sender + receiver rows
// and indices for tile t+1 prefetched into registers during tile t compute.
// ---------------------------------------------------------------------------
__global__ __launch_bounds__(256, 2)
void fused_msg_kernel(const f16* __restrict__ nfh, const float* __restrict__ ef,
                      const int* __restrict__ perm, const int2* __restrict__ ssr,
                      const f16* __restrict__ wbuf, const float* __restrict__ b,
                      float* __restrict__ AGG, int n_edges) {
    __shared__ __align__(16) f16 Alds[NSRC * 64 * H];  // 48 KB
    __shared__ __align__(16) f16 MSG[64 * MSTRIDE];    // 16.5 KB
    __shared__ int SR[64];

    const int t = threadIdx.x;
    const int lane = t & 63;
    const int wid = t >> 6;     // 0..3
    const int l15 = lane & 15;
    const int lg = lane >> 4;
    const int c2 = lane * 2;

    // ---- W fragments in registers: [src][cf][ks], this wave's 32 cols ----
    f16x8 breg[NSRC][2][4];
#pragma unroll
    for (int src = 0; src < NSRC; ++src)
#pragma unroll
        for (int cf = 0; cf < 2; ++cf)
#pragma unroll
            for (int ks = 0; ks < 4; ++ks) {
                const int c = wid * 32 + cf * 16 + l15;
                const int k = ks * 32 + lg * 8;
                unsigned off = ((unsigned)(c * 256 + k * 2)) ^ ((unsigned)((c & 7) << 4));
                breg[src][cf][ks] =
                    *(const f16x8*)((const char*)wbuf + (size_t)src * 32768 + off);
            }

    const float2 bias2 = *(const float2*)&b[c2];
    const int srow = t >> 2;   // staging row 0..63
    const int sq = t & 3;      // staging k-quarter
    const int ntiles = (n_edges + 63) >> 6;
    const int stride = gridDim.x;

    // ---- pipeline registers (all static names) ----
    int cr = 0;                                 // current receiver (for SR)
    int ns = 0, nr = 0, npx = 0;                // indices, next tile
    int4 s0, s1, s2, s3;                        // sender row quarter (64 B f16)
    int4 r0, r1, r2, r3;                        // receiver row quarter (64 B f16)
    float4 e0, e1, e2, e3, e4, e5, e6, e7;      // EF row quarter (128 B fp32)

    int tile = blockIdx.x;
    if (tile < ntiles) {
        const int e = min(tile * 64 + srow, n_edges - 1);
        int2 cv = ssr[e];
        int cs = cv.x; cr = cv.y;
        int cp = perm[e];
        const int4* ps = (const int4*)(nfh + (size_t)cs * H + sq * 32);
        s0 = ps[0]; s1 = ps[1]; s2 = ps[2]; s3 = ps[3];
        const int4* pr = (const int4*)(nfh + (size_t)cr * H + sq * 32);
        r0 = pr[0]; r1 = pr[1]; r2 = pr[2]; r3 = pr[3];
        const float4* pe = (const float4*)(ef + (size_t)cp * H + sq * 32);
        e0 = pe[0]; e1 = pe[1]; e2 = pe[2]; e3 = pe[3];
        e4 = pe[4]; e5 = pe[5]; e6 = pe[6]; e7 = pe[7];
    }
    if (tile + stride < ntiles) {
        const int e = min((tile + stride) * 64 + srow, n_edges - 1);
        int2 nv = ssr[e];
        ns = nv.x; nr = nv.y;
        npx = perm[e];
    }

    for (; tile < ntiles; tile += stride) {
        const int e0base = tile * 64;
        __syncthreads();  // Alds free (prev MFMA done), MSG free (prev reduce done)

        // ---- stage: write prefetched sender + receiver + EF data ----
        {
            unsigned off0 = ((unsigned)(srow * 256 + (sq * 32 + 0) * 2)) ^ ((unsigned)((srow & 7) << 4));
            unsigned off1 = ((unsigned)(srow * 256 + (sq * 32 + 8) * 2)) ^ ((unsigned)((srow & 7) << 4));
            unsigned off2 = ((unsigned)(srow * 256 + (sq * 32 + 16) * 2)) ^ ((unsigned)((srow & 7) << 4));
            unsigned off3 = ((unsigned)(srow * 256 + (sq * 32 + 24) * 2)) ^ ((unsigned)((srow & 7) << 4));
            *(int4*)((char*)Alds + off0) = s0;
            *(int4*)((char*)Alds + off1) = s1;
            *(int4*)((char*)Alds + off2) = s2;
            *(int4*)((char*)Alds + off3) = s3;
            *(int4*)((char*)Alds + 16384 + off0) = r0;
            *(int4*)((char*)Alds + 16384 + off1) = r1;
            *(int4*)((char*)Alds + 16384 + off2) = r2;
            *(int4*)((char*)Alds + 16384 + off3) = r3;
            f16x8 h0, h1, h2, h3;
#pragma unroll
            for (int j = 0; j < 4; ++j) { h0[j] = (f16)(&e0.x)[j]; h0[j + 4] = (f16)(&e1.x)[j]; }
#pragma unroll
            for (int j = 0; j < 4; ++j) { h1[j] = (f16)(&e2.x)[j]; h1[j + 4] = (f16)(&e3.x)[j]; }
#pragma unroll
            for (int j = 0; j < 4; ++j) { h2[j] = (f16)(&e4.x)[j]; h2[j + 4] = (f16)(&e5.x)[j]; }
#pragma unroll
            for (int j = 0; j < 4; ++j) { h3[j] = (f16)(&e6.x)[j]; h3[j + 4] = (f16)(&e7.x)[j]; }
            *(f16x8*)((char*)Alds + 32768 + off0) = h0;
            *(f16x8*)((char*)Alds + 32768 + off1) = h1;
            *(f16x8*)((char*)Alds + 32768 + off2) = h2;
            *(f16x8*)((char*)Alds + 32768 + off3) = h3;
            if (sq == 0) SR[srow] = cr;
        }

        // ---- issue prefetches for next tiles (fly under MFMA + reduce) ----
        int t2s = 0, t2r = 0, t2p = 0;
        if (tile + 2 * stride < ntiles) {
            const int e = min((tile + 2 * stride) * 64 + srow, n_edges - 1);
            int2 t2v = ssr[e];
            t2s = t2v.x; t2r = t2v.y;
            t2p = perm[e];
        }
        if (tile + stride < ntiles) {
            const int4* ps = (const int4*)(nfh + (size_t)ns * H + sq * 32);
            s0 = ps[0]; s1 = ps[1]; s2 = ps[2]; s3 = ps[3];
            const int4* pr = (const int4*)(nfh + (size_t)nr * H + sq * 32);
            r0 = pr[0]; r1 = pr[1]; r2 = pr[2]; r3 = pr[3];
            const float4* pe = (const float4*)(ef + (size_t)npx * H + sq * 32);
            e0 = pe[0]; e1 = pe[1]; e2 = pe[2]; e3 = pe[3];
            e4 = pe[4]; e5 = pe[5]; e6 = pe[6]; e7 = pe[7];
        }
        __syncthreads();  // Alds ready

        // ---- MFMA: 64 rows x this wave's 32 cols, K=384 ----
        f32x4 acc[4][2];
#pragma unroll
        for (int rf = 0; rf < 4; ++rf) {
            acc[rf][0] = (f32x4){0.f, 0.f, 0.f, 0.f};
            acc[rf][1] = (f32x4){0.f, 0.f, 0.f, 0.f};
        }
#pragma unroll
        for (int src = 0; src < NSRC; ++src)
#pragma unroll
            for (int ks = 0; ks < 4; ++ks) {
                f16x8 af[4];
#pragma unroll
                for (int rf = 0; rf < 4; ++rf) {
                    const int row = rf * 16 + l15;
                    const int k = ks * 32 + lg * 8;
                    unsigned off = ((unsigned)(row * 256 + k * 2))
                                   ^ ((unsigned)((row & 7) << 4));
                    af[rf] = *(const f16x8*)((const char*)Alds + (size_t)src * 16384 + off);
                }
#pragma unroll
                for (int rf = 0; rf < 4; ++rf) {
                    acc[rf][0] = __builtin_amdgcn_mfma_f32_16x16x32_f16(
                        af[rf], breg[src][0][ks], acc[rf][0], 0, 0, 0);
                    acc[rf][1] = __builtin_amdgcn_mfma_f32_16x16x32_f16(
                        af[rf], breg[src][1][ks], acc[rf][1], 0, 0, 0);
                }
            }

        // ---- MSG transpose (C/D: col=l15, row=lg*4+q) ----
#pragma unroll
        for (int rf = 0; rf < 4; ++rf)
#pragma unroll
            for (int cf = 0; cf < 2; ++cf)
#pragma unroll
                for (int q = 0; q < 4; ++q)
                    MSG[(rf * 16 + lg * 4 + q) * MSTRIDE + wid * 32 + cf * 16 + l15] =
                        (f16)acc[rf][cf][q];
        __syncthreads();

        // ---- segmented reduce: wave wid owns rows wid*16..+16 ----
        int rarr[16];
#pragma unroll
        for (int j = 0; j < 16; ++j) rarr[j] = SR[wid * 16 + j];
        float ax = 0.f, ay = 0.f;
#pragma unroll
        for (int j = 0; j < 16; ++j) {
            const int e = e0base + wid * 16 + j;
            if (e < n_edges) {
                f16x2 m = *(const f16x2*)&MSG[(wid * 16 + j) * MSTRIDE + c2];
                ax += fmaxf((float)m[0] + bias2.x, 0.f);
                ay += fmaxf((float)m[1] + bias2.y, 0.f);
                bool flush = (j == 15) || (e + 1 >= n_edges) || (rarr[j + 1] != rarr[j]);
                if (flush) {
                    atomicAdd(&AGG[(size_t)rarr[j] * H + c2], ax);
                    atomicAdd(&AGG[(size_t)rarr[j] * H + c2 + 1], ay);
                    ax = 0.f;
                    ay = 0.f;
                }
            }
        }

        // ---- rotate pipeline registers ----
        cr = nr;
        ns = t2s; nr = t2r; npx = t2p;
    }
}

// ---------------------------------------------------------------------------
// LayerNorm(nf + AGG) -> out
// ---------------------------------------------------------------------------
__global__ __launch_bounds__(256, 4)
void ln_agg_kernel(const float* __restrict__ nf, const float* __restrict__ AGG,
                   const float* __restrict__ lnw, const float* __restrict__ lnb,
                   float* __restrict__ out, int n_nodes) {
    const int wv = threadIdx.x >> 6;
    const int lane = threadIdx.x & 63;
    const int row = blockIdx.x * (blockDim.x >> 6) + wv;
    if (row >= n_nodes) return;
    float2 a = ((const float2*)(nf + (size_t)row * H))[lane];
    float2 g = ((const float2*)(AGG + (size_t)row * H))[lane];
    float vx = a.x + g.x, vy = a.y + g.y;

    float s = vx + vy;
#pragma unroll
    for (int m = 32; m; m >>= 1) s += __shfl_xor(s, m, 64);
    float mu = s * (1.f / H);
    float dx = vx - mu, dy = vy - mu;
    float q = dx * dx + dy * dy;
#pragma unroll
    for (int m = 32; m; m >>= 1) q += __shfl_xor(q, m, 64);
    float rs = rsqrtf(q * (1.f / H) + 1e-5f);

    float2 w2 = ((const float2*)lnw)[lane];
    float2 b2 = ((const float2*)lnb)[lane];
    float2 o;
    o.x = dx * rs * w2.x + b2.x;
    o.y = dy * rs * w2.y + b2.y;
    ((float2*)(out + (size_t)row * H))[lane] = o;
}

// ---------------------------------------------------------------------------
// Fallback (small ws): naive edge pass + LN
// ---------------------------------------------------------------------------
__global__ void naive_edge_kernel(const float* __restrict__ nf, const int* __restrict__ s,
                                  const int* __restrict__ r, const float* __restrict__ ef,
                                  const float* __restrict__ W, const float* __restrict__ b,
                                  float* __restrict__ out, int n_edges) {
    int e = blockIdx.x * 2 + (threadIdx.x >> 7);
    int c = threadIdx.x & 127;
    if (e >= n_edges) return;
    int se = s[e], re = r[e];
    float acc = b[c];
    for (int k = 0; k < H; ++k) {
        acc += nf[(size_t)se * H + k] * W[(size_t)k * H + c];
        acc += nf[(size_t)re * H + k] * W[(size_t)(H + k) * H + c];
        acc += ef[(size_t)e * H + k] * W[(size_t)(2 * H + k) * H + c];
    }
    atomicAdd(&out[(size_t)re * H + c], fmaxf(acc, 0.f));
}

__global__ __launch_bounds__(256, 4)
void ln_kernel(const float* __restrict__ nf, const float* __restrict__ lnw,
               const float* __restrict__ lnb, float* __restrict__ out, int n_nodes) {
    const int wv = threadIdx.x >> 6;
    const int lane = threadIdx.x & 63;
    const int row = blockIdx.x * (blockDim.x >> 6) + wv;
    if (row >= n_nodes) return;
    float2 a = ((const float2*)(nf + (size_t)row * H))[lane];
    float2 g = ((float2*)(out + (size_t)row * H))[lane];
    float vx = a.x + g.x, vy = a.y + g.y;
    float s = vx + vy;
#pragma unroll
    for (int m = 32; m; m >>= 1) s += __shfl_xor(s, m, 64);
    float mu = s * (1.f / H);
    float dx = vx - mu, dy = vy - mu;
    float q = dx * dx + dy * dy;
#pragma unroll
    for (int m = 32; m; m >>= 1) q += __shfl_xor(q, m, 64);
    float rs = rsqrtf(q * (1.f / H) + 1e-5f);
    float2 w2 = ((const float2*)lnw)[lane];
    float2 b2 = ((const float2*)lnb)[lane];
    float2 o;
    o.x = dx * rs * w2.x + b2.x;
    o.y = dy * rs * w2.y + b2.y;
    ((float2*)(out + (size_t)row * H))[lane] = o;
}

// ---------------------------------------------------------------------------
extern "C" void kernel_launch(void* const* d_in, const int* in_sizes, int n_in,
                              void* d_out, int out_size, void* d_ws, size_t ws_size,
                              hipStream_t stream) {
    const float* nf        = (const float*)d_in[0];
    const int*   senders   = (const int*)d_in[1];
    const int*   receivers = (const int*)d_in[2];
    const float* ef        = (const float*)d_in[3];
    const float* W         = (const float*)d_in[4];
    const float* b         = (const float*)d_in[5];
    const float* lnw       = (const float*)d_in[6];
    const float* lnb       = (const float*)d_in[7];
    float* out = (float*)d_out;

    const int n_nodes = in_sizes[0] / H;  // 50000
    const int n_edges = in_sizes[1];      // 800000
    const int nfelem = n_nodes * H;

    // ws carve-out (256B aligned)
    size_t o = 0;
    auto carve = [&](size_t bytes) { size_t r = o; o += (bytes + 255) & ~(size_t)255; return r; };
    const size_t o_wbuf   = carve((size_t)NSRC * H * H * sizeof(f16));   // 96 KB
    const size_t o_nfh    = carve((size_t)nfelem * sizeof(f16));         // 12.8 MB
    const size_t o_cnt    = carve((size_t)n_nodes * 4);
    const size_t o_rowptr = carve((size_t)(n_nodes + 1) * 4);
    const size_t o_cursor = carve((size_t)n_nodes * 4);
    const size_t o_perm   = carve((size_t)n_edges * 4);
    const size_t o_ssr    = carve((size_t)n_edges * 8);
    const size_t o_agg    = carve((size_t)nfelem * sizeof(float));       // 25.6 MB
    const size_t need_full = o;

    char* ws = (char*)d_ws;

    if (ws_size >= need_full) {
        f16* wbuf   = (f16*)(ws + o_wbuf);
        f16* nfh    = (f16*)(ws + o_nfh);
        int* cnt    = (int*)(ws + o_cnt);
        int* rowptr = (int*)(ws + o_rowptr);
        int* cursor = (int*)(ws + o_cursor);
        int* perm   = (int*)(ws + o_perm);
        int2* ssr   = (int2*)(ws + o_ssr);
        float* AGG  = (float*)(ws + o_agg);

        setup_kernel<<<2048, 256, 0, stream>>>(W, wbuf, cnt, (float4*)AGG,
                                               n_nodes, nfelem / 4, nf, nfh, nfelem / 4);
        hist_kernel<<<(n_edges / 4 + 255) / 256, 256, 0, stream>>>(receivers, cnt, n_edges);
        scan_kernel<<<1, 1024, 0, stream>>>(cnt, rowptr, cursor, n_nodes);
        scatter_kernel<<<(n_edges + 255) / 256, 256, 0, stream>>>(
            senders, receivers, cursor, perm, ssr, n_edges);

        fused_msg_kernel<<<1024, 256, 0, stream>>>(nfh, ef, perm, ssr, wbuf, b,
                                                   AGG, n_edges);
        ln_agg_kernel<<<(n_nodes + 3) / 4, 256, 0, stream>>>(nf, AGG, lnw, lnb, out, n_nodes);
    } else {
        hipMemsetAsync(d_out, 0, (size_t)nfelem * sizeof(float), stream);
        naive_edge_kernel<<<(n_edges + 1) / 2, 256, 0, stream>>>(
            nf, senders, receivers, ef, W, b, out, n_edges);
        ln_kernel<<<(n_nodes + 3) / 4, 256, 0, stream>>>(nf, lnw, lnb, out, n_nodes);
    }
}